// Round 3
// baseline (65.208 us; speedup 1.0000x reference)
//
#include <hip/hip_runtime.h>

// CensoredLoss:
//   d_in[0] = outputs [B, T=512, 4] f32
//   d_in[1] = targets [B, T=512, 5] f32
// out: scalar f32 = -sum(mask*(loss1+loss2)) / count
// mask[b,t] = 1 iff t <= t_max[b]; t_max[b] = last t with any targets[b,t,:] != 0
// (targets >= 0, so per-t sum > 0 <=> any element nonzero).
//
// Pipelined: one __syncthreads per row. Each iteration issues outputs loads
// (bmax known from previous iter) + next row's targets loads up front, then
// computes loss from double-buffered LDS while loads are in flight.

#define EPSF 1e-8f
#define T_DIM 512

__device__ __forceinline__ int tmax_upd(int tmax, const float4& r, int fbase) {
    if (r.x != 0.f) tmax = max(tmax, (fbase + 0) / 5);
    if (r.y != 0.f) tmax = max(tmax, (fbase + 1) / 5);
    if (r.z != 0.f) tmax = max(tmax, (fbase + 2) / 5);
    if (r.w != 0.f) tmax = max(tmax, (fbase + 3) / 5);
    return tmax;
}

__global__ __launch_bounds__(256) void censored_loss_partial(
    const float4* __restrict__ outs4,   // [B*T] float4
    const float4* __restrict__ tgts4,   // [B*T*5/4] float4
    float* __restrict__ part_loss,      // [B]
    int* __restrict__ part_cnt,         // [B]
    int B)
{
    __shared__ float tg[2][T_DIM * 5];     // 2 x 10240 B
    __shared__ int   wmax[2][4];
    __shared__ float wsum[2][4];

    const int tid = threadIdx.x;
    const int wave = tid >> 6, lane = tid & 63;
    const bool third = tid < 128;          // 640 float4 = 256+256+128
    const int stride = gridDim.x;

    // ---- prologue: stage first row into buffer 0, compute its bmax ----
    {
        const float4* trow = tgts4 + (size_t)blockIdx.x * 640;
        float4 r0 = trow[tid];
        float4 r1 = trow[tid + 256];
        float4 r2{0.f, 0.f, 0.f, 0.f};
        if (third) r2 = trow[tid + 512];

        int tmax = -1;
        tmax = tmax_upd(tmax, r0, 4 * tid);
        tmax = tmax_upd(tmax, r1, 4 * (tid + 256));
        if (third) tmax = tmax_upd(tmax, r2, 4 * (tid + 512));

        ((float4*)tg[0])[tid] = r0;
        ((float4*)tg[0])[tid + 256] = r1;
        if (third) ((float4*)tg[0])[tid + 512] = r2;

        #pragma unroll
        for (int off = 32; off > 0; off >>= 1)
            tmax = max(tmax, __shfl_down(tmax, off));
        if (lane == 0) wmax[0][wave] = tmax;
        __syncthreads();
    }

    int cur = 0;
    for (int b = blockIdx.x; b < B; b += stride) {
        const int nb = b + stride;
        const bool have = nb < B;
        const int bmax = max(max(wmax[cur][0], wmax[cur][1]),
                             max(wmax[cur][2], wmax[cur][3]));

        // -- issue outputs loads for row b (predicated on mask) --
        float4 o0{0.f, 0.f, 0.f, 0.f}, o1{0.f, 0.f, 0.f, 0.f};
        const size_t obase = (size_t)b * T_DIM;
        if (tid <= bmax)       o0 = outs4[obase + tid];
        if (tid + 256 <= bmax) o1 = outs4[obase + tid + 256];

        // -- issue targets loads for row b+stride --
        float4 r0{0.f,0.f,0.f,0.f}, r1{0.f,0.f,0.f,0.f}, r2{0.f,0.f,0.f,0.f};
        if (have) {
            const float4* trow = tgts4 + (size_t)nb * 640;
            r0 = trow[tid];
            r1 = trow[tid + 256];
            if (third) r2 = trow[tid + 512];
        }

        // -- loss for row b from LDS[cur] + outputs regs --
        const float* tgc = tg[cur];
        float sum = 0.f;
        if (tid <= bmax) {
            const float* p = tgc + tid * 5;
            const float cens = 1.0f - (o0.x + o0.y + o0.z + o0.w);
            sum += p[0] * __logf(cens + EPSF)
                 + p[1] * __logf(o0.x + EPSF)
                 + p[2] * __logf(o0.y + EPSF)
                 + p[3] * __logf(o0.z + EPSF)
                 + p[4] * __logf(o0.w + EPSF);
        }
        if (tid + 256 <= bmax) {
            const float* p = tgc + (tid + 256) * 5;
            const float cens = 1.0f - (o1.x + o1.y + o1.z + o1.w);
            sum += p[0] * __logf(cens + EPSF)
                 + p[1] * __logf(o1.x + EPSF)
                 + p[2] * __logf(o1.y + EPSF)
                 + p[3] * __logf(o1.z + EPSF)
                 + p[4] * __logf(o1.w + EPSF);
        }
        #pragma unroll
        for (int off = 32; off > 0; off >>= 1)
            sum += __shfl_down(sum, off);
        if (lane == 0) wsum[cur][wave] = sum;

        // -- next row: tmax from regs, write into LDS[cur^1] --
        if (have) {
            int tmax = -1;
            tmax = tmax_upd(tmax, r0, 4 * tid);
            tmax = tmax_upd(tmax, r1, 4 * (tid + 256));
            if (third) tmax = tmax_upd(tmax, r2, 4 * (tid + 512));

            float* tgn = tg[cur ^ 1];
            ((float4*)tgn)[tid] = r0;
            ((float4*)tgn)[tid + 256] = r1;
            if (third) ((float4*)tgn)[tid + 512] = r2;

            #pragma unroll
            for (int off = 32; off > 0; off >>= 1)
                tmax = max(tmax, __shfl_down(tmax, off));
            if (lane == 0) wmax[cur ^ 1][wave] = tmax;
        }

        __syncthreads();   // the ONE barrier per row

        if (tid == 0) {
            part_loss[b] = wsum[cur][0] + wsum[cur][1] + wsum[cur][2] + wsum[cur][3];
            part_cnt[b]  = bmax + 1;
        }
        cur ^= 1;
    }
}

__global__ __launch_bounds__(256) void censored_loss_finalize(
    const float* __restrict__ part_loss,
    const int* __restrict__ part_cnt,
    float* __restrict__ out, int nblocks)
{
    double ls = 0.0;
    long long cs = 0;
    for (int i = threadIdx.x; i < nblocks; i += 256) {
        ls += (double)part_loss[i];
        cs += (long long)part_cnt[i];
    }
    #pragma unroll
    for (int off = 32; off > 0; off >>= 1) {
        ls += __shfl_down(ls, off);
        cs += __shfl_down(cs, off);
    }
    __shared__ double lw[4];
    __shared__ long long cw[4];
    const int wave = threadIdx.x >> 6, lane = threadIdx.x & 63;
    if (lane == 0) { lw[wave] = ls; cw[wave] = cs; }
    __syncthreads();
    if (threadIdx.x == 0) {
        const double L = lw[0] + lw[1] + lw[2] + lw[3];
        const long long C = cw[0] + cw[1] + cw[2] + cw[3];
        out[0] = (C > 0) ? (float)(-L / (double)C) : 0.0f;
    }
}

extern "C" void kernel_launch(void* const* d_in, const int* in_sizes, int n_in,
                              void* d_out, int out_size, void* d_ws, size_t ws_size,
                              hipStream_t stream) {
    const float4* outs4 = (const float4*)d_in[0];
    const float4* tgts4 = (const float4*)d_in[1];
    float* out = (float*)d_out;

    const int B = in_sizes[1] / (T_DIM * 5);

    float* part_loss = (float*)d_ws;
    int* part_cnt = (int*)((char*)d_ws + (size_t)B * sizeof(float));

    const int nblocks = (B < 2048) ? B : 2048;
    censored_loss_partial<<<nblocks, 256, 0, stream>>>(outs4, tgts4, part_loss, part_cnt, B);
    censored_loss_finalize<<<1, 256, 0, stream>>>(part_loss, part_cnt, out, B);
}

// Round 4
// 61.232 us; speedup vs baseline: 1.0649x; 1.0649x over previous
//
#include <hip/hip_runtime.h>

// CensoredLoss:
//   d_in[0] = outputs [B, T=512, 4] f32
//   d_in[1] = targets [B, T=512, 5] f32
// out: scalar f32 = -sum(mask*(loss1+loss2)) / count
// mask[b,t] = 1 iff t <= t_max[b]; t_max[b] = last t with sum(targets[b,t,:]) > 0.
//
// One wave per row, zero barriers, zero LDS. Lane l owns t = 8l..8l+7
// (= 40 contiguous floats = 10 aligned float4 of the targets row).
// tmax via shfl_xor butterfly; outputs loads predicated on t <= tmax.

#define EPSF 1e-8f
#define T_DIM 512
#define NSLOT 256

__global__ __launch_bounds__(256) void censored_loss_rows(
    const float4* __restrict__ outs4,   // [B*512] float4
    const float4* __restrict__ tgts4,   // [B*640] float4
    float* __restrict__ loss_slots,     // [NSLOT]
    int* __restrict__ cnt_slots,        // [NSLOT]
    int B)
{
    const int lane = threadIdx.x & 63;
    const int row = (blockIdx.x * 256 + threadIdx.x) >> 6;   // global wave id
    if (row >= B) return;

    // ---- load this lane's 40 targets floats (10 aligned float4) ----
    const float4* trow = tgts4 + (size_t)row * 640 + lane * 10;
    float tg[40];
    #pragma unroll
    for (int k = 0; k < 10; ++k) {
        const float4 v = trow[k];
        tg[4 * k + 0] = v.x;
        tg[4 * k + 1] = v.y;
        tg[4 * k + 2] = v.z;
        tg[4 * k + 3] = v.w;
    }

    // ---- per-lane last nonzero t, then wave butterfly max ----
    int tmax = -1;
    #pragma unroll
    for (int j = 0; j < 8; ++j) {
        const float s = tg[5 * j] + tg[5 * j + 1] + tg[5 * j + 2]
                      + tg[5 * j + 3] + tg[5 * j + 4];
        if (s > 0.f) tmax = 8 * lane + j;   // j ascending: plain overwrite
    }
    #pragma unroll
    for (int off = 1; off < 64; off <<= 1)
        tmax = max(tmax, __shfl_xor(tmax, off));

    // ---- masked loss: outputs loads predicated on t <= tmax ----
    const float4* orow = outs4 + (size_t)row * T_DIM;
    float sum = 0.f;
    #pragma unroll
    for (int j = 0; j < 8; ++j) {
        const int t = 8 * lane + j;
        if (t <= tmax) {
            const float4 o = orow[t];
            const float cens = 1.0f - (o.x + o.y + o.z + o.w);
            sum += tg[5 * j + 0] * __logf(cens + EPSF)
                 + tg[5 * j + 1] * __logf(o.x + EPSF)
                 + tg[5 * j + 2] * __logf(o.y + EPSF)
                 + tg[5 * j + 3] * __logf(o.z + EPSF)
                 + tg[5 * j + 4] * __logf(o.w + EPSF);
        }
    }
    #pragma unroll
    for (int off = 1; off < 64; off <<= 1)
        sum += __shfl_xor(sum, off);

    if (lane == 0) {
        atomicAdd(&loss_slots[row & (NSLOT - 1)], sum);
        atomicAdd(&cnt_slots[row & (NSLOT - 1)], tmax + 1);
    }
}

__global__ __launch_bounds__(256) void censored_loss_finalize(
    const float* __restrict__ loss_slots,
    const int* __restrict__ cnt_slots,
    float* __restrict__ out)
{
    const int tid = threadIdx.x;
    double ls = (double)loss_slots[tid];
    long long cs = (long long)cnt_slots[tid];
    #pragma unroll
    for (int off = 32; off > 0; off >>= 1) {
        ls += __shfl_down(ls, off);
        cs += __shfl_down(cs, off);
    }
    __shared__ double lw[4];
    __shared__ long long cw[4];
    const int wave = tid >> 6, lane = tid & 63;
    if (lane == 0) { lw[wave] = ls; cw[wave] = cs; }
    __syncthreads();
    if (tid == 0) {
        const double L = lw[0] + lw[1] + lw[2] + lw[3];
        const long long C = cw[0] + cw[1] + cw[2] + cw[3];
        out[0] = (C > 0) ? (float)(-L / (double)C) : 0.0f;
    }
}

extern "C" void kernel_launch(void* const* d_in, const int* in_sizes, int n_in,
                              void* d_out, int out_size, void* d_ws, size_t ws_size,
                              hipStream_t stream) {
    const float4* outs4 = (const float4*)d_in[0];
    const float4* tgts4 = (const float4*)d_in[1];
    float* out = (float*)d_out;

    const int B = in_sizes[1] / (T_DIM * 5);

    float* loss_slots = (float*)d_ws;
    int* cnt_slots = (int*)((char*)d_ws + NSLOT * sizeof(float));

    hipMemsetAsync(d_ws, 0, NSLOT * (sizeof(float) + sizeof(int)), stream);

    const int nblocks = (B + 3) / 4;   // 4 waves (rows) per 256-thread block
    censored_loss_rows<<<nblocks, 256, 0, stream>>>(outs4, tgts4, loss_slots, cnt_slots, B);
    censored_loss_finalize<<<1, 256, 0, stream>>>(loss_slots, cnt_slots, out);
}